// Round 4
// baseline (177.892 us; speedup 1.0000x reference)
//
#include <hip/hip_runtime.h>
#include <stdint.h>

// Reference: pos += fl32(vel*dt); vel += fl32(fl32(-9.81)*fl32(0.01)); record pos.
// The np reference is the f32 scan; we emulate its rounding staircase exactly via
// piecewise-constant-increment runs (~209 of them), verified by a wave-parallel
// endpoint check. r4: analytic run-length BOUNDS moved from f64 (3 IEEE double
// divides ~1700cy/event) to fast f32 (__fdividef + f32 frexp) — bounds are
// estimates only; the ballot verify guarantees exactness and an underestimate
// merely splits a run (still exact).

static constexpr long long NSTEPS = 10000000LL;  // output rows
static constexpr long long NSTART = 131072LL;    // start of event emulation (even!)
static constexpr int LDSRUNS = 1024;             // LDS-cached run-table capacity

__global__ __launch_bounds__(64) void prepass(
        const float* __restrict__ pos0, const float* __restrict__ vel0,
        long long* __restrict__ run_n0, double* __restrict__ run_pos,
        double* __restrict__ run_inc, long long* __restrict__ count, long long cap) {
    const int lane = threadIdx.x;  // single wave; state replicated wave-uniform
    const float dtf  = 0.01f;
    const float gdtf = __fmul_rn(-9.81f, dtf);
    const double dtd = (double)dtf, gdtd = (double)gdtf;
    const double p0y = (double)pos0[1], v0y = (double)vel0[1];

    // Anchor at NSTART via exact-arithmetic closed form, snapped to the f32 grid.
    const double nA  = (double)NSTART;
    double pos = (double)(float)(p0y + dtd * (nA * v0y) +
                                 (dtd * gdtd) * (nA * (nA - 1.0) * 0.5));
    double vel = (double)(float)(v0y + nA * gdtd);
    float pf = (float)pos, vf = (float)vel;     // exact mirrors (state is on f32 grid)

    long long n = NSTART, cnt = 0;
    while (n < NSTEPS - 1 && cnt < cap) {
        // True f32 increments at current state (state mirrors are exact).
        const float dstep = __fmul_rn(vf, dtf);
        const float pn1   = __fadd_rn(pf, dstep);
        const float vn1   = __fadd_rn(vf, gdtf);
        const double inc  = (double)pn1 - pos;
        const double cv   = (double)vn1 - vel;
        const float incf  = (float)inc;
        const float cvf   = (float)cv;
        const long long rem = (NSTEPS - 1) - n;

        // ---- Fast f32 run-length ESTIMATES (verify below guarantees exactness;
        //      an underestimate only splits a run, which stays exact). ----
        long long La = rem, Lb = rem, Lc = rem;
        if (incf != 0.0f && pf != 0.0f) {           // pos binade exit
            int k; (void)frexpf(pf, &k);            // |pf| in [2^(k-1), 2^k)
            float s = pf < 0.0f ? -1.0f : 1.0f;
            float B = ((pf < 0.0f) == (incf < 0.0f)) ? ldexpf(s, k) : ldexpf(s, k - 1);
            float r = __fdividef(B - pf, incf);
            La = (!(r < 4.0e9f)) ? rem : ((long long)r - 1);
            if (La < 0) La = 0;
        }
        if (cvf != 0.0f && vf != 0.0f) {            // vel binade exit
            int k; (void)frexpf(vf, &k);
            float s = vf < 0.0f ? -1.0f : 1.0f;
            float B = ((vf < 0.0f) == (cvf < 0.0f)) ? ldexpf(s, k) : ldexpf(s, k - 1);
            float r = __fdividef(B - vf, cvf);
            Lb = (!(r < 4.0e9f)) ? rem : ((long long)r - 1);
            if (Lb < 0) Lb = 0;
        }
        if (cvf != 0.0f && pf != 0.0f) {            // pos-increment rounding-edge crossing
            int k; (void)frexpf(pf, &k);
            float ulp = ldexpf(1.0f, k - 24);
            float dd  = cvf * dtf;
            float T   = incf + (dd < 0.0f ? -0.5f : 0.5f) * ulp;
            float jx  = __fdividef(__fdividef(T, dtf) - vf, cvf);
            Lc = (!(jx < 4.0e9f)) ? rem : ((long long)jx + 2);
            if (Lc < 1) Lc = 1;
        }
        long long Lhi = La < Lb ? La : Lb;
        if (Lc < Lhi) Lhi = Lc;
        Lhi += 2;                                   // slack; window below absorbs it
        if (Lhi > rem) Lhi = rem;
        if (Lhi < 1) Lhi = 1;

        // Wave-parallel endpoint verify: 64 candidates per round, highest valid wins.
        long long L = 1;
        long long base = Lhi;
        for (int round = 0; round < 20; ++round) {
            const long long candL = base - 63 + (long long)lane;
            bool valid = false;
            if (candL >= 1) {
                const double pe = pos + (double)(candL - 1) * inc;
                const double ve = vel + (double)(candL - 1) * cv;
                const float pef = (float)pe, vef = (float)ve;
                const float d2  = __fmul_rn(vef, dtf);
                const float pn2 = __fadd_rn(pef, d2);
                const float vn2 = __fadd_rn(vef, gdtf);
                valid = ((double)pn2 - pe == inc) && ((double)vn2 - ve == cv);
            }
            const unsigned long long m = __ballot(valid);
            if (m != 0ULL) { L = base - 63 + (long long)(63 - __clzll(m)); break; }
            base -= 64;
            if (base < 1) break;                    // L=1 fallback (always valid)
        }
        if (L < 1) L = 1;
        if (L > rem) L = rem;

        if (lane == 0) { run_n0[cnt] = n; run_pos[cnt] = pos; run_inc[cnt] = inc; }
        ++cnt;
        pos += (double)L * inc;                     // exact: grid-aligned dyadics
        vel += (double)L * cv;
        n   += L;
        pf = (float)pos; vf = (float)vel;           // exact (state is on f32 grid)
    }
    if (lane == 0) *count = cnt;
}

__device__ __forceinline__ double closed_y(long long m, double p0y, double v0y,
                                           double dtd, double gdtd) {
    double md = (double)m;
    return p0y + dtd * (md * v0y) + (dtd * gdtd) * (md * (md - 1.0) * 0.5);
}

__global__ __launch_bounds__(256) void fill(
        const float* __restrict__ pos0, const float* __restrict__ vel0,
        const long long* __restrict__ run_n0, const double* __restrict__ run_pos,
        const double* __restrict__ run_inc, const long long* __restrict__ count,
        float4* __restrict__ out, long long npairs) {
    __shared__ int    s_n0[LDSRUNS];
    __shared__ double s_pos[LDSRUNS];
    __shared__ double s_inc[LDSRUNS];

    const float dtf  = 0.01f;
    const float gdtf = __fmul_rn(-9.81f, dtf);
    const double dtd = (double)dtf, gdtd = (double)gdtf;
    const double p0x = (double)pos0[0], p0y = (double)pos0[1];
    const double v0y = (double)vel0[1];
    const double cx  = (double)__fmul_rn(vel0[0], dtf);  // constant f32 x-increment
    (void)gdtf;

    const int cnt = (int)*count;
    const bool lds_ok = (cnt > 0 && cnt <= LDSRUNS);
    if (lds_ok) {
        for (int i = threadIdx.x; i < cnt; i += blockDim.x) {
            s_n0[i]  = (int)run_n0[i];
            s_pos[i] = run_pos[i];
            s_inc[i] = run_inc[i];
        }
    }
    __syncthreads();

    const long long stride = (long long)gridDim.x * blockDim.x;
    for (long long i = (long long)blockIdx.x * blockDim.x + threadIdx.x;
         i < npairs; i += stride) {
        const long long m0 = 2 * i, m1 = m0 + 1;
        float4 o;
        o.x = (float)(p0x + (double)m0 * cx);
        o.z = (float)(p0x + (double)m1 * cx);

        if (m1 < NSTART) {  // NSTART even => m0,m1 on the same side
            o.y = (float)closed_y(m0, p0y, v0y, dtd, gdtd);
            o.w = (float)closed_y(m1, p0y, v0y, dtd, gdtd);
        } else if (lds_ok) {
            int lo = 0, hi = cnt - 1;
            const int t0 = (int)m0;
            while (lo < hi) {
                int mid = (lo + hi + 1) >> 1;
                if (s_n0[mid] <= t0) lo = mid; else hi = mid - 1;
            }
            o.y = (float)(s_pos[lo] + (double)(m0 - s_n0[lo]) * s_inc[lo]);
            const int r1 = (lo + 1 < cnt && s_n0[lo + 1] <= (int)m1) ? lo + 1 : lo;
            o.w = (float)(s_pos[r1] + (double)(m1 - s_n0[r1]) * s_inc[r1]);
        } else {            // fallback: search the global table
            long long lo = 0, hi = (long long)cnt - 1;
            while (lo < hi) {
                long long mid = (lo + hi + 1) >> 1;
                if (run_n0[mid] <= m0) lo = mid; else hi = mid - 1;
            }
            o.y = (float)(run_pos[lo] + (double)(m0 - run_n0[lo]) * run_inc[lo]);
            long long r1 = (lo + 1 < cnt && run_n0[lo + 1] <= m1) ? lo + 1 : lo;
            o.w = (float)(run_pos[r1] + (double)(m1 - run_n0[r1]) * run_inc[r1]);
        }
        out[i] = o;
    }
}

extern "C" void kernel_launch(void* const* d_in, const int* in_sizes, int n_in,
                              void* d_out, int out_size, void* d_ws, size_t ws_size,
                              hipStream_t stream) {
    // Inputs: [0] ball_mass (unused), [1] initial_position[2], [2] initial_velocity[2].
    const float* pos0 = (const float*)d_in[1];
    const float* vel0 = (const float*)d_in[2];

    long long cap = ((long long)ws_size - 64) / 24;  // 3 arrays of 8B each
    if (cap > 16384) cap = 16384;
    if (cap < 1) cap = 1;

    long long* cnt    = (long long*)d_ws;
    long long* rn0    = (long long*)((char*)d_ws + 64);
    double*    rpos   = (double*)((char*)d_ws + 64 + cap * 8);
    double*    rinc   = (double*)((char*)d_ws + 64 + cap * 16);

    prepass<<<1, 64, 0, stream>>>(pos0, vel0, rn0, rpos, rinc, cnt, cap);

    const long long npairs = (long long)out_size / 4;  // 5,000,000 float4s
    fill<<<2048, 256, 0, stream>>>(pos0, vel0, rn0, rpos, rinc, cnt,
                                   (float4*)d_out, npairs);
}

// Round 5
// 51.525 us; speedup vs baseline: 3.4525x; 3.4525x over previous
//
#include <hip/hip_runtime.h>
#include <stdint.h>

// Reference: pos += fl32(vel*dt); vel += fl32(fl32(-9.81)*fl32(0.01)); record pos.
// We emulate the f32 scan's rounding staircase exactly via piecewise-constant-
// increment runs, verified by a wave-parallel endpoint ballot. r5 changes:
//  (a) NSTART 131072 -> 1e6: events ~213 -> ~100 (density ~ 1/n; closed-form
//      drift at 1e6 is <= ~1.1e8 even assuming linear growth vs r1's measured
//      1.07e9 at 1e7 — fits the 9.99e8 budget with margin).
//  (b) tight run-length bounds: exact f64 numerators (grid-aligned dyadics)
//      x fast f32 __fdividef — accurate to ±1, so ONE ballot round suffices
//      (r3/r4 identical timings implicated multi-round walk-down as the cost).

static constexpr long long NSTEPS = 10000000LL;  // output rows
static constexpr long long NSTART = 1000000LL;   // start of event emulation (even!)
static constexpr int LDSRUNS = 1024;             // LDS-cached run-table capacity

__global__ __launch_bounds__(64) void prepass(
        const float* __restrict__ pos0, const float* __restrict__ vel0,
        long long* __restrict__ run_n0, double* __restrict__ run_pos,
        double* __restrict__ run_inc, long long* __restrict__ count, long long cap) {
    const int lane = threadIdx.x;  // single wave; state replicated wave-uniform
    const float dtf  = 0.01f;
    const float gdtf = __fmul_rn(-9.81f, dtf);
    const double dtd = (double)dtf, gdtd = (double)gdtf;
    const double p0y = (double)pos0[1], v0y = (double)vel0[1];

    // Anchor at NSTART via exact-arithmetic closed form, snapped to the f32 grid.
    const double nA  = (double)NSTART;
    double pos = (double)(float)(p0y + dtd * (nA * v0y) +
                                 (dtd * gdtd) * (nA * (nA - 1.0) * 0.5));
    double vel = (double)(float)(v0y + nA * gdtd);
    float pf = (float)pos, vf = (float)vel;     // exact mirrors (state on f32 grid)

    long long n = NSTART, cnt = 0;
    while (n < NSTEPS - 1 && cnt < cap) {
        // True f32 increments at current state (state mirrors are exact).
        const float dstep = __fmul_rn(vf, dtf);
        const float pn1   = __fadd_rn(pf, dstep);
        const float vn1   = __fadd_rn(vf, gdtf);
        const double inc  = (double)pn1 - pos;
        const double cv   = (double)vn1 - vel;
        const long long rem = (NSTEPS - 1) - n;

        // ---- Tight run-length bounds: exact f64 numerators, fast f32 divide.
        //      (Estimates only; ballot verify below guarantees exactness —
        //       an under/overshoot merely splits a run or costs one round.)
        long long La = rem, Lb = rem, Lc = rem;
        if (inc != 0.0 && pos != 0.0) {             // pos binade exit
            int k; (void)frexp(pos, &k);            // |pos| in [2^(k-1), 2^k)
            double s = pos < 0.0 ? -1.0 : 1.0;
            double B = ((pos < 0.0) == (inc < 0.0)) ? ldexp(s, k) : ldexp(s, k - 1);
            float r = __fdividef((float)(B - pos), (float)inc);
            La = (r >= 0.0f && r < 4.0e9f) ? ((long long)r - 1) : rem;
            if (La < 0) La = 0;
        }
        if (cv != 0.0 && vel != 0.0) {              // vel binade exit
            int k; (void)frexp(vel, &k);
            double s = vel < 0.0 ? -1.0 : 1.0;
            double B = ((vel < 0.0) == (cv < 0.0)) ? ldexp(s, k) : ldexp(s, k - 1);
            float r = __fdividef((float)(B - vel), (float)cv);
            Lb = (r >= 0.0f && r < 4.0e9f) ? ((long long)r - 1) : rem;
            if (Lb < 0) Lb = 0;
        }
        if (cv != 0.0 && pos != 0.0) {              // pos-increment cell crossing
            int k; (void)frexp(pos, &k);
            const double ulp = ldexp(1.0, k - 24);  // f32 ulp of pos's binade
            const double d0  = (double)dstep;       // current fl32(vel*dt), exact
            const double dd  = cv * dtd;            // per-step drift of d
            const double T   = inc + (dd < 0.0 ? -0.5 : 0.5) * ulp;  // next cell edge
            float r = __fdividef((float)(T - d0), (float)dd);
            Lc = (r >= 0.0f && r < 4.0e9f) ? ((long long)r + 2) : rem;
            if (Lc < 1) Lc = 1;
        }
        long long Lhi = La < Lb ? La : Lb;
        if (Lc < Lhi) Lhi = Lc;
        Lhi += 3;                                   // bound fuzz; window absorbs it
        if (Lhi > rem) Lhi = rem;
        if (Lhi < 1) Lhi = 1;

        // Wave-parallel endpoint verify: 64 candidates/round, highest valid wins.
        // With tight bounds this resolves in ONE round.
        long long L = 1;
        long long base = Lhi;
        for (int round = 0; round < 20; ++round) {
            const long long candL = base - 63 + (long long)lane;
            bool valid = false;
            if (candL >= 1) {
                const double pe = pos + (double)(candL - 1) * inc;  // exact dyadics
                const double ve = vel + (double)(candL - 1) * cv;
                const float pef = (float)pe, vef = (float)ve;
                const float d2  = __fmul_rn(vef, dtf);
                const float pn2 = __fadd_rn(pef, d2);
                const float vn2 = __fadd_rn(vef, gdtf);
                valid = ((double)pn2 - pe == inc) && ((double)vn2 - ve == cv);
            }
            const unsigned long long m = __ballot(valid);
            if (m != 0ULL) { L = base - 63 + (long long)(63 - __clzll(m)); break; }
            base -= 64;
            if (base < 1) break;                    // L=1 fallback (always valid)
        }
        if (L < 1) L = 1;
        if (L > rem) L = rem;

        if (lane == 0) { run_n0[cnt] = n; run_pos[cnt] = pos; run_inc[cnt] = inc; }
        ++cnt;
        pos += (double)L * inc;                     // exact: grid-aligned dyadics
        vel += (double)L * cv;
        n   += L;
        pf = (float)pos; vf = (float)vel;           // exact (state on f32 grid)
    }
    if (lane == 0) *count = cnt;
}

__device__ __forceinline__ double closed_y(long long m, double p0y, double v0y,
                                           double dtd, double gdtd) {
    double md = (double)m;
    return p0y + dtd * (md * v0y) + (dtd * gdtd) * (md * (md - 1.0) * 0.5);
}

__global__ __launch_bounds__(256) void fill(
        const float* __restrict__ pos0, const float* __restrict__ vel0,
        const long long* __restrict__ run_n0, const double* __restrict__ run_pos,
        const double* __restrict__ run_inc, const long long* __restrict__ count,
        float4* __restrict__ out, long long npairs) {
    __shared__ int    s_n0[LDSRUNS];
    __shared__ double s_pos[LDSRUNS];
    __shared__ double s_inc[LDSRUNS];

    const float dtf  = 0.01f;
    const double dtd = (double)dtf;
    const double gdtd = (double)__fmul_rn(-9.81f, dtf);
    const double p0x = (double)pos0[0], p0y = (double)pos0[1];
    const double v0y = (double)vel0[1];
    const double cx  = (double)__fmul_rn(vel0[0], dtf);  // constant f32 x-increment

    const int cnt = (int)*count;
    const bool lds_ok = (cnt > 0 && cnt <= LDSRUNS);
    if (lds_ok) {
        for (int i = threadIdx.x; i < cnt; i += blockDim.x) {
            s_n0[i]  = (int)run_n0[i];
            s_pos[i] = run_pos[i];
            s_inc[i] = run_inc[i];
        }
    }
    __syncthreads();

    const long long stride = (long long)gridDim.x * blockDim.x;
    for (long long i = (long long)blockIdx.x * blockDim.x + threadIdx.x;
         i < npairs; i += stride) {
        const long long m0 = 2 * i, m1 = m0 + 1;
        float4 o;
        o.x = (float)(p0x + (double)m0 * cx);
        o.z = (float)(p0x + (double)m1 * cx);

        if (m1 < NSTART) {  // NSTART even => m0,m1 on the same side
            o.y = (float)closed_y(m0, p0y, v0y, dtd, gdtd);
            o.w = (float)closed_y(m1, p0y, v0y, dtd, gdtd);
        } else if (lds_ok) {
            int lo = 0, hi = cnt - 1;
            const int t0 = (int)m0;
            while (lo < hi) {
                int mid = (lo + hi + 1) >> 1;
                if (s_n0[mid] <= t0) lo = mid; else hi = mid - 1;
            }
            o.y = (float)(s_pos[lo] + (double)(m0 - s_n0[lo]) * s_inc[lo]);
            const int r1 = (lo + 1 < cnt && s_n0[lo + 1] <= (int)m1) ? lo + 1 : lo;
            o.w = (float)(s_pos[r1] + (double)(m1 - s_n0[r1]) * s_inc[r1]);
        } else {            // fallback: search the global table
            long long lo = 0, hi = (long long)cnt - 1;
            while (lo < hi) {
                long long mid = (lo + hi + 1) >> 1;
                if (run_n0[mid] <= m0) lo = mid; else hi = mid - 1;
            }
            o.y = (float)(run_pos[lo] + (double)(m0 - run_n0[lo]) * run_inc[lo]);
            long long r1 = (lo + 1 < cnt && run_n0[lo + 1] <= m1) ? lo + 1 : lo;
            o.w = (float)(run_pos[r1] + (double)(m1 - run_n0[r1]) * run_inc[r1]);
        }
        out[i] = o;
    }
}

extern "C" void kernel_launch(void* const* d_in, const int* in_sizes, int n_in,
                              void* d_out, int out_size, void* d_ws, size_t ws_size,
                              hipStream_t stream) {
    // Inputs: [0] ball_mass (unused), [1] initial_position[2], [2] initial_velocity[2].
    const float* pos0 = (const float*)d_in[1];
    const float* vel0 = (const float*)d_in[2];

    long long cap = ((long long)ws_size - 64) / 24;  // 3 arrays of 8B each
    if (cap > 16384) cap = 16384;
    if (cap < 1) cap = 1;

    long long* cnt    = (long long*)d_ws;
    long long* rn0    = (long long*)((char*)d_ws + 64);
    double*    rpos   = (double*)((char*)d_ws + 64 + cap * 8);
    double*    rinc   = (double*)((char*)d_ws + 64 + cap * 16);

    prepass<<<1, 64, 0, stream>>>(pos0, vel0, rn0, rpos, rinc, cnt, cap);

    const long long npairs = (long long)out_size / 4;  // 5,000,000 float4s
    fill<<<2048, 256, 0, stream>>>(pos0, vel0, rn0, rpos, rinc, cnt,
                                   (float4*)d_out, npairs);
}